// Round 5
// baseline (168.948 us; speedup 1.0000x reference)
//
#include <hip/hip_runtime.h>
#include <math.h>

// Problem constants (fixed by reference setup_inputs)
#define NN 8192
#define SS 32
#define DD 32
#define KK 1024
#define OUT_ELEMS ((size_t)NN * SS * DD)   // 8388608; loss scalar at out[OUT_ELEMS]

// loss = S * (1 + BETA) * sum_sq / (N*S*D)
#define LOSS_SCALE (32.0f * 1.001f / 8388608.0f)

typedef _Float16 half8  __attribute__((ext_vector_type(8)));
typedef float   floatx4  __attribute__((ext_vector_type(4)));
typedef float   floatx16 __attribute__((ext_vector_type(16)));

#define NTILES 32                      // 1024 codewords / 32 per 32x32 MFMA tile
#define WAVES 16                       // 1024-thread blocks
#define BLK_ROWS (WAVES * 32)          // 512 rows per block (32 rows/wave)
#define NBLOCKS ((NN / BLK_ROWS) * SS) // 512 main blocks (1/CU, 2 rounds)

// SESSION NOTE (R11): R6/R8/R9/R10 — four schedules (lockstep-dbuf, glload-
// staged, LDS-resident barrier-free, manual A/B SWP) ALL land 85-90us,
// MfmaUtil ~25%, VGPR ~50. VGPR=56 after R10's manual pipeline proves the
// compiler re-sinks loads and re-serializes regardless of source order.
// This round changes the WORK SHAPE instead: v_mfma_f32_32x32x16_f16.
// Per wave-tile: 32 rows x 32 kcols, 6 chained MFMAs = 2x MFMA work per
// latency point, half the latency points, and 32x32 is ~17% cheaper/FLOP
// (floor 24.8 -> 20.7us). C/D layout HW-verified (m74/m101); A/B layout is
// the unique generalization of the 16x16x32 layout proven in R6-R10.

// ---- workspace layout (d_ws): needs ~4.14 MB ----
#define W2P_OFF  4096                          // part[NBLOCKS] lives at 0
#define WHP_OFF  (W2P_OFF + SS * KK * 4)       // w2P: 128 KB
#define WLP_OFF  (WHP_OFF + SS * KK * DD * 2)  // WhP: 2 MB, WlP: 2 MB

typedef const __attribute__((address_space(1))) void* gas_p;
typedef __attribute__((address_space(3))) void* las_p;

__device__ __forceinline__ void gll16(const void* g, void* l) {
    __builtin_amdgcn_global_load_lds((gas_p)g, (las_p)l, 16, 0, 0);
}
__device__ __forceinline__ void gll4(const void* g, void* l) {
    __builtin_amdgcn_global_load_lds((gas_p)g, (las_p)l, 4, 0, 0);
}

#define MFMA32(a, b, c) __builtin_amdgcn_mfma_f32_32x32x16_f16((a), (b), (c), 0, 0, 0)

// ---- one-time W preprocessing: f16 hi/lo split + row norms ----
// WhP/WlP layout (linear in u): [s][g 0..31][q 0..1][lane 0..63][8 halves].
// Entry (s,g,q,l) holds codeword k = g*32 + (l&31), dims d = q*16 + (l>>5)*8 + j
// == the B-fragment bytes for MFMA tile g, K-step q, in gll16 lane order.
__global__ __launch_bounds__(256) void w_pre(const float* __restrict__ W,
                                             _Float16* __restrict__ WhP,
                                             _Float16* __restrict__ WlP,
                                             float* __restrict__ w2P) {
    const int u  = blockIdx.x * 256 + threadIdx.x;   // 0..131071
    const int s  = u >> 12;
    const int r  = u & 4095;
    const int g  = r >> 7;            // tile (32 codewords)
    const int q  = (r >> 6) & 1;      // K-step
    const int l  = u & 63;
    const int k  = g * 32 + (l & 31);
    const int db = q * 16 + (l >> 5) * 8;
    const float* src = W + ((size_t)s * KK + k) * DD + db;
    const float4 va = ((const float4*)src)[0];
    const float4 vb = ((const float4*)src)[1];
    const float v[8] = {va.x, va.y, va.z, va.w, vb.x, vb.y, vb.z, vb.w};
    half8 h8, l8;
    #pragma unroll
    for (int j = 0; j < 8; ++j) {
        const float x = v[j];
        const _Float16 h = (_Float16)x;
        h8[j] = h;
        l8[j] = (_Float16)(x - (float)h);
    }
    *(half8*)(WhP + (size_t)u * 8) = h8;
    *(half8*)(WlP + (size_t)u * 8) = l8;

    // norms: one thread per (s,k) for the first SS*KK threads
    if (u < SS * KK) {
        const float* row = W + (size_t)u * DD;
        float ps = 0.0f;
        #pragma unroll
        for (int c = 0; c < 8; ++c) {
            const float4 w4 = ((const float4*)row)[c];
            ps = fmaf(w4.x, w4.x, ps); ps = fmaf(w4.y, w4.y, ps);
            ps = fmaf(w4.z, w4.z, ps); ps = fmaf(w4.w, w4.w, ps);
        }
        w2P[u] = ps;
    }
}

__global__ __launch_bounds__(1024, 4) void vq_fused(const float* __restrict__ z,
                                                    const float* __restrict__ W,
                                                    const _Float16* __restrict__ WhP,
                                                    const _Float16* __restrict__ WlP,
                                                    const float* __restrict__ w2P,
                                                    float* __restrict__ out,
                                                    float* __restrict__ part) {
    // Whole per-s codebook resident in LDS: 132.3 KB static (<160 KB).
    __shared__ _Float16 bufH[NTILES][2][64][8];  // 64 KB  [tile][kstep][lane][8]
    __shared__ _Float16 bufL[NTILES][2][64][8];  // 64 KB
    __shared__ float    w2b[KK];                 // 4 KB
    __shared__ int      lds_idx[WAVES][32];      // 2 KB
    __shared__ float    lds_part[WAVES];

    const int s    = blockIdx.x & (SS - 1);
    const int n0b  = (blockIdx.x >> 5) * BLK_ROWS;
    const int tid  = threadIdx.x;
    const int wv   = tid >> 6;
    const int lane = tid & 63;
    const int rowa = lane & 31;      // A row / B col / argmin column
    const int q5   = lane >> 5;      // which 8-dim slice within a K-step

    const float* __restrict__ Ws = W + (size_t)s * KK * DD;
    const int n0w = n0b + wv * 32;

    // ---- stage the whole codebook: 8 gll16 + 1 gll4 per wave ----
    // (byte-linear copy; LDS dest = wave-uniform base + lane*16, m104 rule)
    {
        const char* gH = (const char*)(WhP + (size_t)s * (NTILES * 2 * 512));
        const char* gL = (const char*)(WlP + (size_t)s * (NTILES * 2 * 512));
        char* lH = (char*)&bufH[0][0][0][0];
        char* lL = (char*)&bufL[0][0][0][0];
        const int wvB = wv * 1024;             // 64 lanes * 16 B
        #pragma unroll
        for (int i = 0; i < 4; ++i) {
            const int off = i * 16384 + wvB;
            gll16(gH + off + lane * 16, lH + off);
            gll16(gL + off + lane * 16, lL + off);
        }
        const float* g2 = w2P + (size_t)s * KK + wv * 64;
        gll4(g2 + lane, (char*)w2b + wv * 256);
    }

    // ---- A-fragments: (-2*z) hi/lo, per K-step. row=lane&31, k=(lane>>5)*8+j ----
    half8 zh0, zl0, zh1, zl1;
    {
        const float* zp = z + (size_t)(n0w + rowa) * (SS * DD) + s * DD + q5 * 8;
        const float4 va = ((const float4*)zp)[0];        // dims q5*8 .. +3
        const float4 vb = ((const float4*)zp)[1];        // dims q5*8+4 .. +7
        const float4 vc = ((const float4*)(zp + 16))[0]; // dims 16+q5*8 ..
        const float4 vd = ((const float4*)(zp + 16))[1];
        const float s0[8] = {va.x, va.y, va.z, va.w, vb.x, vb.y, vb.z, vb.w};
        const float s1[8] = {vc.x, vc.y, vc.z, vc.w, vd.x, vd.y, vd.z, vd.w};
        #pragma unroll
        for (int j = 0; j < 8; ++j) {
            const float v0 = -2.0f * s0[j];
            const _Float16 h0 = (_Float16)v0;
            zh0[j] = h0; zl0[j] = (_Float16)(v0 - (float)h0);
            const float v1 = -2.0f * s1[j];
            const _Float16 h1 = (_Float16)v1;
            zh1[j] = h1; zl1[j] = (_Float16)(v1 - (float)h1);
        }
    }

    floatx16 best;
    int bi[16];
    #pragma unroll
    for (int i = 0; i < 16; ++i) { best[i] = INFINITY; bi[i] = 0; }

    __syncthreads();   // single barrier: drains gll vmcnt; codebook visible

    // ---- K loop: 32 tiles of 32 codewords. d2 = w2 - 2 z.w (3-term hi/lo),
    // K=32 contraction as 2 chained K=16 steps. ----
    #pragma unroll 2
    for (int g = 0; g < NTILES; ++g) {
        const half8 bh0 = *(const half8*)&bufH[g][0][lane][0];
        const half8 bh1 = *(const half8*)&bufH[g][1][lane][0];
        const half8 bl0 = *(const half8*)&bufL[g][0][lane][0];
        const half8 bl1 = *(const half8*)&bufL[g][1][lane][0];
        const float w2v = w2b[g * 32 + rowa];
        floatx16 c0;
        #pragma unroll
        for (int i = 0; i < 16; ++i) c0[i] = w2v;
        floatx16 acc;
        acc = MFMA32(zh0, bh0, c0);
        acc = MFMA32(zh1, bh1, acc);
        acc = MFMA32(zl0, bh0, acc);
        acc = MFMA32(zl1, bh1, acc);
        acc = MFMA32(zh0, bl0, acc);
        acc = MFMA32(zh1, bl1, acc);
        #pragma unroll
        for (int i = 0; i < 16; ++i) {   // strict <, lowest tile wins ties
            if (acc[i] < best[i]) { best[i] = acc[i]; bi[i] = g; }
        }
    }

    // ---- cross-lane argmin over the 32 k-columns (lanes sharing a row);
    // C/D row = (i&3) + 8*(i>>2) + 4*q5, col = lane&31. Lower k wins ties. ----
    #pragma unroll
    for (int i = 0; i < 16; ++i) {
        float v = best[i];
        int   k = bi[i] * 32 + rowa;
        #pragma unroll
        for (int m = 1; m < 32; m <<= 1) {
            const float vo = __shfl_xor(v, m, 64);
            const int   ko = __shfl_xor(k, m, 64);
            if (vo < v || (vo == v && ko < k)) { v = vo; k = ko; }
        }
        if (rowa == 0) lds_idx[wv][(i & 3) + 8 * (i >> 2) + 4 * q5] = k;
    }
    __syncthreads();

    // ---- epilogue: 2 lanes per n-row (16 floats each); zq = fp32 W[s,k*] ----
    const int r  = rowa;
    const int dh = q5 * 16;
    const int krow = lds_idx[wv][r];
    const float* wsrc = Ws + (size_t)krow * DD + dh;
    const size_t zoff = (size_t)(n0w + r) * (SS * DD) + s * DD + dh;
    const float* zsrc = z + zoff;
    float* od = out + zoff;
    float sq = 0.0f;
    #pragma unroll
    for (int cc = 0; cc < 4; ++cc) {
        const float4 wq = ((const float4*)wsrc)[cc];
        const float4 zv = ((const float4*)zsrc)[cc];
        const float d0 = wq.x - zv.x, d1 = wq.y - zv.y;
        const float d2 = wq.z - zv.z, d3 = wq.w - zv.w;
        sq = fmaf(d0, d0, sq); sq = fmaf(d1, d1, sq);
        sq = fmaf(d2, d2, sq); sq = fmaf(d3, d3, sq);
        ((float4*)od)[cc] = wq;
    }
    #pragma unroll
    for (int off = 32; off > 0; off >>= 1) sq += __shfl_down(sq, off, 64);

    // per-block partial -> distinct address; NO same-address atomics
    if (lane == 0) lds_part[wv] = sq;
    __syncthreads();
    if (tid == 0) {
        float t = 0.0f;
        #pragma unroll
        for (int w = 0; w < WAVES; ++w) t += lds_part[w];
        part[blockIdx.x] = t;
    }
}

// Tiny final reduce: 1 block sums the per-block partials.
__global__ __launch_bounds__(256) void vq_loss(const float* __restrict__ part,
                                               float* __restrict__ out) {
    __shared__ float l[4];
    const int tid = threadIdx.x;
    float sum = 0.0f;
    #pragma unroll
    for (int i = 0; i < NBLOCKS / 256; ++i) sum += part[tid + i * 256];
    #pragma unroll
    for (int off = 32; off > 0; off >>= 1) sum += __shfl_down(sum, off, 64);
    if ((tid & 63) == 0) l[tid >> 6] = sum;
    __syncthreads();
    if (tid == 0) out[OUT_ELEMS] = (l[0] + l[1] + l[2] + l[3]) * LOSS_SCALE;
}

extern "C" void kernel_launch(void* const* d_in, const int* in_sizes, int n_in,
                              void* d_out, int out_size, void* d_ws, size_t ws_size,
                              hipStream_t stream) {
    const float* z = (const float*)d_in[0];   // (8192, 1024) fp32
    const float* W = (const float*)d_in[1];   // (32, 1024, 32) fp32
    float* out  = (float*)d_out;              // 8388608 zq_st + 1 loss

    char* ws = (char*)d_ws;                   // needs ~4.14 MB
    float*    part = (float*)ws;              // [0, 4KB)
    float*    w2P  = (float*)(ws + W2P_OFF);  // 128 KB
    _Float16* WhP  = (_Float16*)(ws + WHP_OFF); // 2 MB
    _Float16* WlP  = (_Float16*)(ws + WLP_OFF); // 2 MB

    // one-time W split (4 MB read): 131072 threads
    w_pre<<<dim3(512), dim3(256), 0, stream>>>(W, WhP, WlP, w2P);
    // 512 blocks: blockIdx&31 = s, blockIdx>>5 = 512-row n-tile.
    vq_fused<<<dim3(NBLOCKS), dim3(1024), 0, stream>>>(z, W, WhP, WlP, w2P, out, part);
    vq_loss<<<dim3(1), dim3(256), 0, stream>>>(part, out);
}

// Round 6
// 154.044 us; speedup vs baseline: 1.0968x; 1.0968x over previous
//
#include <hip/hip_runtime.h>
#include <math.h>

// Problem constants (fixed by reference setup_inputs)
#define NN 8192
#define SS 32
#define DD 32
#define KK 1024
#define OUT_ELEMS ((size_t)NN * SS * DD)   // 8388608; loss scalar at out[OUT_ELEMS]

// loss = S * (1 + BETA) * sum_sq / (N*S*D)
#define LOSS_SCALE (32.0f * 1.001f / 8388608.0f)

typedef _Float16 half8  __attribute__((ext_vector_type(8)));
typedef float   floatx4 __attribute__((ext_vector_type(4)));

#define NTILES 64                      // 1024 codewords / 16 per MFMA tile
#define WAVES 16                       // 1024-thread blocks
#define BLK_ROWS (WAVES * 32)          // 512 rows per block (RG=2 x 16)
#define NBLOCKS ((NN / BLK_ROWS) * SS) // 512 main blocks (1/CU, 2 rounds)

// SESSION NOTE (R12): R6-R11: five schedules, two MFMA shapes, ALL 85-95us,
// MfmaUtil ~25%, VGPR ~50. VGPR~50 proves every source-level pipeline was
// discarded: compiler re-sinks ds_reads and re-serializes (per-tile chain
// ds_read -> lgkmcnt(0) -> 3-dep MFMA -> dependent compares ~= 400cyc of
// which 116 MFMA = the measured 25%). Per guide rule #18 / m97 lesson, the
// fix is ASM-ANCHORED pipelining: volatile-asm ds_read triple per tile into
// a 4-buffer named rotation, counted s_waitcnt lgkmcnt(3) (2 tiles in
// flight, never drained) + sched_barrier(0), compares deferred one tile
// (acc A/B rotation). Verification signal: VGPR must jump to ~100.

// ---- workspace layout (d_ws): ~4.33 MB ----
#define W2P_OFF  4096                          // part[NBLOCKS] lives at 0
#define WP_OFF   (W2P_OFF + SS * KK * 4)       // w2P: 128 KB
// WP: [s][tile 0..63][H/L][lane 0..63][8 halves] = 128 KB per s, 4 MB total

typedef const __attribute__((address_space(1))) void* gas_p;
typedef __attribute__((address_space(3))) void* las_p;

__device__ __forceinline__ void gll16(const void* g, void* l) {
    __builtin_amdgcn_global_load_lds((gas_p)g, (las_p)l, 16, 0, 0);
}
__device__ __forceinline__ void gll4(const void* g, void* l) {
    __builtin_amdgcn_global_load_lds((gas_p)g, (las_p)l, 4, 0, 0);
}

#define MFMA16(a, b, c) __builtin_amdgcn_mfma_f32_16x16x32_f16((a), (b), (c), 0, 0, 0)

// ---- one-time W preprocessing: f16 hi/lo split + row norms, fragment order ----
// WP entry (s,g,{H,L},l) holds codeword k = g*16 + (l&15), dims d=(l>>4)*8..+7.
__global__ __launch_bounds__(256) void w_pre(const float* __restrict__ W,
                                             _Float16* __restrict__ WP,
                                             float* __restrict__ w2P) {
    const int u    = blockIdx.x * 256 + threadIdx.x;   // 0..131071
    const int s    = u >> 12;
    const int g    = (u >> 6) & 63;
    const int l    = u & 63;
    const int col  = l & 15;
    const int quad = l >> 4;
    const int k    = g * 16 + col;
    const float* src = W + ((size_t)s * KK + k) * DD + quad * 8;
    const float4 va = ((const float4*)src)[0];
    const float4 vb = ((const float4*)src)[1];
    const float v[8] = {va.x, va.y, va.z, va.w, vb.x, vb.y, vb.z, vb.w};
    half8 h8, l8; float ps = 0.0f;
    #pragma unroll
    for (int j = 0; j < 8; ++j) {
        const float x = v[j];
        ps = fmaf(x, x, ps);
        const _Float16 h = (_Float16)x;
        h8[j] = h;
        l8[j] = (_Float16)(x - (float)h);
    }
    ps += __shfl_xor(ps, 16, 64);
    ps += __shfl_xor(ps, 32, 64);
    _Float16* base = WP + ((size_t)(s * 64 + g) * 2) * 512;
    *(half8*)(base + l * 8) = h8;          // [g][H][l][8]
    *(half8*)(base + 512 + l * 8) = l8;    // [g][L][l][8]
    if (quad == 0) w2P[s * KK + k] = ps;
}

__global__ __launch_bounds__(1024, 4) void vq_fused(const float* __restrict__ z,
                                                    const float* __restrict__ W,
                                                    const _Float16* __restrict__ WP,
                                                    const float* __restrict__ w2P,
                                                    float* __restrict__ out,
                                                    float* __restrict__ part) {
    // Whole per-s codebook resident in LDS: 134.1 KB static (<160 KB).
    __shared__ _Float16 bufHL[NTILES][2][64][8];  // 128 KB  [tile][H/L][lane][8]
    __shared__ float    w2b[KK];                  // 4 KB
    __shared__ int      lds_idx[WAVES][32];       // 2 KB
    __shared__ float    lds_part[WAVES];

    const int s    = blockIdx.x & (SS - 1);
    const int n0b  = (blockIdx.x >> 5) * BLK_ROWS;
    const int tid  = threadIdx.x;
    const int wv   = tid >> 6;
    const int lane = tid & 63;
    const int col  = lane & 15;
    const int quad = lane >> 4;

    const float* __restrict__ Ws = W + (size_t)s * KK * DD;
    const int n0w = n0b + wv * 32;

    // ---- stage the whole codebook: 8 gll16 + 1 gll4 per wave ----
    {
        const char* gW = (const char*)(WP + (size_t)s * (NTILES * 2 * 512));
        char* lW = (char*)&bufHL[0][0][0][0];
        const int wvB = wv * 1024;             // 64 lanes * 16 B
        #pragma unroll
        for (int i = 0; i < 8; ++i) {
            const int off = i * 16384 + wvB;
            gll16(gW + off + lane * 16, lW + off);
        }
        const float* g2 = w2P + (size_t)s * KK + wv * 64;
        gll4(g2 + lane, (char*)w2b + wv * 256);
    }

    // ---- A-fragments: (-2*z) hi/lo. A[m=col][d=quad*8+j]. ----
    half8 zh0, zl0, zh1, zl1;
    {
        const float* zp0 = z + (size_t)(n0w + col) * (SS * DD) + s * DD + quad * 8;
        const float* zp1 = zp0 + 16 * (SS * DD);
        const float4 va = ((const float4*)zp0)[0];
        const float4 vb = ((const float4*)zp0)[1];
        const float4 vc = ((const float4*)zp1)[0];
        const float4 vd = ((const float4*)zp1)[1];
        const float s0[8] = {va.x, va.y, va.z, va.w, vb.x, vb.y, vb.z, vb.w};
        const float s1[8] = {vc.x, vc.y, vc.z, vc.w, vd.x, vd.y, vd.z, vd.w};
        #pragma unroll
        for (int j = 0; j < 8; ++j) {
            const float v0 = -2.0f * s0[j];
            const _Float16 h0 = (_Float16)v0;
            zh0[j] = h0; zl0[j] = (_Float16)(v0 - (float)h0);
            const float v1 = -2.0f * s1[j];
            const _Float16 h1 = (_Float16)v1;
            zh1[j] = h1; zl1[j] = (_Float16)(v1 - (float)h1);
        }
    }

    floatx4 best0, best1;
    int bi0[4], bi1[4];
    best0 = best1 = (floatx4){INFINITY, INFINITY, INFINITY, INFINITY};
    bi0[0] = bi0[1] = bi0[2] = bi0[3] = 0;
    bi1[0] = bi1[1] = bi1[2] = bi1[3] = 0;

    __syncthreads();   // drains gll vmcnt; codebook visible

    // ---- asm-anchored pipelined K loop --------------------------------
    unsigned hladdr = (unsigned)(unsigned long long)(las_p)&bufHL[0][0][0][0]
                      + (unsigned)(lane * 16);
    unsigned w2addr = (unsigned)(unsigned long long)(las_p)&w2b[0]
                      + (unsigned)(col * 4);

#define ISSUE(FH, FL, FW, HO, LO, WO)                                       \
    asm volatile("ds_read_b128 %0, %3 offset:%c5\n\t"                       \
                 "ds_read_b128 %1, %3 offset:%c6\n\t"                       \
                 "ds_read_b32  %2, %4 offset:%c7"                           \
                 : "=&v"(FH), "=&v"(FL), "=&v"(FW)                          \
                 : "v"(hladdr), "v"(w2addr), "i"(HO), "i"(LO), "i"(WO))

#define WAITL(N) do {                                                       \
    asm volatile("s_waitcnt lgkmcnt(%c0)" :: "i"(N) : "memory");            \
    __builtin_amdgcn_sched_barrier(0);                                      \
} while (0)

#define MTILE(FH, FL, FW, A0, A1) do {                                      \
    const floatx4 c0_ = {FW, FW, FW, FW};                                   \
    A0 = MFMA16(zh0, FH, c0_);                                              \
    A1 = MFMA16(zh1, FH, c0_);                                              \
    A0 = MFMA16(zl0, FH, A0);                                               \
    A1 = MFMA16(zl1, FH, A1);                                               \
    A0 = MFMA16(zh0, FL, A0);                                               \
    A1 = MFMA16(zh1, FL, A1);                                               \
} while (0)

#define CTILE(P0, P1, TK) do {                                              \
    const int tk_ = (TK);                                                   \
    _Pragma("unroll")                                                       \
    for (int i_ = 0; i_ < 4; ++i_) {  /* strict <, lowest tile wins ties */ \
        if (P0[i_] < best0[i_]) { best0[i_] = P0[i_]; bi0[i_] = tk_; }      \
        if (P1[i_] < best1[i_]) { best1[i_] = P1[i_]; bi1[i_] = tk_; }      \
    }                                                                       \
} while (0)

    half8 f0h, f0l, f1h, f1l, f2h, f2l, f3h, f3l;
    float f0w, f1w, f2w, f3w;
    floatx4 aA0, aA1, aB0, aB1;
    aB0 = aB1 = (floatx4){INFINITY, INFINITY, INFINITY, INFINITY};

    // prologue: tiles 0,1 in flight (6 LDS ops)
    ISSUE(f0h, f0l, f0w, 0, 1024, 0);
    ISSUE(f1h, f1l, f1w, 2048, 3072, 64);

    int t4 = 0;
    #pragma unroll 1
    for (int g = 0; g < 15; ++g) {     // tiles 0..59; issue up to tile 61
        WAITL(3); ISSUE(f2h, f2l, f2w, 4096, 5120, 128);
        MTILE(f0h, f0l, f0w, aA0, aA1); CTILE(aB0, aB1, t4 - 1);
        WAITL(3); ISSUE(f3h, f3l, f3w, 6144, 7168, 192);
        MTILE(f1h, f1l, f1w, aB0, aB1); CTILE(aA0, aA1, t4);
        WAITL(3); ISSUE(f0h, f0l, f0w, 8192, 9216, 256);
        MTILE(f2h, f2l, f2w, aA0, aA1); CTILE(aB0, aB1, t4 + 1);
        WAITL(3); ISSUE(f1h, f1l, f1w, 10240, 11264, 320);
        MTILE(f3h, f3l, f3w, aB0, aB1); CTILE(aA0, aA1, t4 + 2);
        hladdr += 8192; w2addr += 256; t4 += 4;
    }
    // peeled tail: tiles 60..63 (base now at tile 60)
    WAITL(3); ISSUE(f2h, f2l, f2w, 4096, 5120, 128);   // tile 62
    MTILE(f0h, f0l, f0w, aA0, aA1); CTILE(aB0, aB1, 59);
    WAITL(3); ISSUE(f3h, f3l, f3w, 6144, 7168, 192);   // tile 63
    MTILE(f1h, f1l, f1w, aB0, aB1); CTILE(aA0, aA1, 60);
    WAITL(3);
    MTILE(f2h, f2l, f2w, aA0, aA1); CTILE(aB0, aB1, 61);
    WAITL(0);
    MTILE(f3h, f3l, f3w, aB0, aB1); CTILE(aA0, aA1, 62);
    CTILE(aB0, aB1, 63);

    // ---- cross-lane argmin over the 16 k-columns; lower k wins ties ----
#define REDUCE(BEST, BI, RG) do {                                           \
    _Pragma("unroll")                                                       \
    for (int i = 0; i < 4; ++i) {                                           \
        float v = BEST[i];                                                  \
        int   k = BI[i] * 16 + col;                                         \
        _Pragma("unroll")                                                   \
        for (int m = 1; m < 16; m <<= 1) {                                  \
            const float vo = __shfl_xor(v, m, 64);                          \
            const int   ko = __shfl_xor(k, m, 64);                          \
            if (vo < v || (vo == v && ko < k)) { v = vo; k = ko; }          \
        }                                                                   \
        if (col == 0) lds_idx[wv][(RG) * 16 + quad * 4 + i] = k;            \
    }                                                                       \
} while (0)

    REDUCE(best0, bi0, 0);
    REDUCE(best1, bi1, 1);
    __syncthreads();

    // ---- epilogue: 2 lanes per n-row (16 floats each); zq = fp32 W[s,k*] ----
    const int r  = lane & 31;
    const int dh = (lane >> 5) * 16;
    const int krow = lds_idx[wv][r];
    const float* wsrc = Ws + (size_t)krow * DD + dh;
    const size_t zoff = (size_t)(n0w + r) * (SS * DD) + s * DD + dh;
    const float* zsrc = z + zoff;
    float* od = out + zoff;
    float sq = 0.0f;
    #pragma unroll
    for (int cc = 0; cc < 4; ++cc) {
        const float4 wq = ((const float4*)wsrc)[cc];
        const float4 zv = ((const float4*)zsrc)[cc];
        const float d0 = wq.x - zv.x, d1 = wq.y - zv.y;
        const float d2 = wq.z - zv.z, d3 = wq.w - zv.w;
        sq = fmaf(d0, d0, sq); sq = fmaf(d1, d1, sq);
        sq = fmaf(d2, d2, sq); sq = fmaf(d3, d3, sq);
        ((float4*)od)[cc] = wq;
    }
    #pragma unroll
    for (int off = 32; off > 0; off >>= 1) sq += __shfl_down(sq, off, 64);

    // per-block partial -> distinct address; NO same-address atomics
    if (lane == 0) lds_part[wv] = sq;
    __syncthreads();
    if (tid == 0) {
        float t = 0.0f;
        #pragma unroll
        for (int w = 0; w < WAVES; ++w) t += lds_part[w];
        part[blockIdx.x] = t;
    }
}

// Tiny final reduce: 1 block sums the per-block partials.
__global__ __launch_bounds__(256) void vq_loss(const float* __restrict__ part,
                                               float* __restrict__ out) {
    __shared__ float l[4];
    const int tid = threadIdx.x;
    float sum = 0.0f;
    #pragma unroll
    for (int i = 0; i < NBLOCKS / 256; ++i) sum += part[tid + i * 256];
    #pragma unroll
    for (int off = 32; off > 0; off >>= 1) sum += __shfl_down(sum, off, 64);
    if ((tid & 63) == 0) l[tid >> 6] = sum;
    __syncthreads();
    if (tid == 0) out[OUT_ELEMS] = (l[0] + l[1] + l[2] + l[3]) * LOSS_SCALE;
}

extern "C" void kernel_launch(void* const* d_in, const int* in_sizes, int n_in,
                              void* d_out, int out_size, void* d_ws, size_t ws_size,
                              hipStream_t stream) {
    const float* z = (const float*)d_in[0];   // (8192, 1024) fp32
    const float* W = (const float*)d_in[1];   // (32, 1024, 32) fp32
    float* out  = (float*)d_out;              // 8388608 zq_st + 1 loss

    char* ws = (char*)d_ws;                   // ~4.33 MB
    float*    part = (float*)ws;              // [0, 4KB)
    float*    w2P  = (float*)(ws + W2P_OFF);  // 128 KB
    _Float16* WP   = (_Float16*)(ws + WP_OFF); // 4 MB

    // one-time W split (4 MB read): 131072 threads
    w_pre<<<dim3(512), dim3(256), 0, stream>>>(W, WP, w2P);
    // 512 blocks: blockIdx&31 = s, blockIdx>>5 = 512-row n-tile.
    vq_fused<<<dim3(NBLOCKS), dim3(1024), 0, stream>>>(z, W, WP, w2P, out, part);
    vq_loss<<<dim3(1), dim3(256), 0, stream>>>(part, out);
}